// Round 1
// 336.802 us; speedup vs baseline: 1.0373x; 1.0373x over previous
//
#include <hip/hip_runtime.h>
#include <cstdint>
#include <math.h>

// Problem constants
#define Bsz 4
#define Lsz 1024
#define Dsz 256
#define Hsz 8
#define HD  2048          // H*D
#define NROWS (Bsz*Lsz)   // 4096
#define INV_TEMP 0.0625f  // 1/sqrt(256)

typedef __attribute__((ext_vector_type(8))) short bf16x8;
typedef __attribute__((ext_vector_type(4))) float f32x4;

__device__ inline unsigned short f2bf(float f) {
    union { float f; unsigned u; } x; x.f = f;
    unsigned r = x.u + 0x7fffu + ((x.u >> 16) & 1u);
    return (unsigned short)(r >> 16);
}
__device__ inline float bf2f(unsigned short u) {
    union { unsigned u; float f; } x; x.u = (unsigned)u << 16; return x.f;
}

#define GBL(p) ((const __attribute__((address_space(1))) unsigned int*)(p))
#define LDS(p) ((__attribute__((address_space(3))) unsigned int*)(p))

// C = alpha * A @ B^T.  A [M,K] bf16 lda; Bm [N,K] bf16 ldb.
// Tile TMv x TNv, BK=64, XOR-swizzled LDS staging + ds_read_b128 frags.
// 4 waves as 2x2 quadrants of (TMv/2)x(TNv/2).
// EPI: 0 = plain store; 1 = scores (clamp*mask, exp*mask, bf16; mask is bf16); 2 = pv (scale by invs[row], bf16)
// DB: 0 = single-buffer 2-barrier loop (use when 3+ wgs/CU resident);
//     1 = double-buffered prefetch, 1 barrier/k-step (use when grid-limited to <=2 wgs/CU:
//         LDS doubling is free, and the stage for tile k+1 is issued BEFORE compute of tile k,
//         so __syncthreads' implicit vmcnt(0) drain lands a full compute-phase later).
template <int TMv, int TNv, typename OutT, int EPI, int MINW, int DB>
__global__ __launch_bounds__(256, MINW) void gemm_bt(
    const unsigned short* __restrict__ A, const unsigned short* __restrict__ Bm,
    OutT* __restrict__ C,
    int K, int lda, int ldb, int ldc, int inner,
    long long sA1, long long sA2, long long sB1, long long sB2,
    long long sC1, long long sC2, float alpha,
    const unsigned short* __restrict__ maskb, long long sM2,
    const float* __restrict__ invs, long long sI1, long long sI2)
{
    constexpr int WMv = TMv / 2, WNv = TNv / 2;
    constexpr int IT = TMv / 32, JT = TNv / 32;
    constexpr int APASS = TMv / 32, NPASS = (TMv + TNv) / 32;
    constexpr int TILE = (TMv + TNv) * 64;   // ushorts per k-tile

    const int z  = blockIdx.z;
    const int i1 = z / inner;
    const int i2 = z % inner;
    A  += (size_t)i1 * sA1 + (size_t)i2 * sA2;
    Bm += (size_t)i1 * sB1 + (size_t)i2 * sB2;
    C  += (size_t)i1 * sC1 + (size_t)i2 * sC2;
    if (EPI == 1) maskb += (size_t)i2 * sM2;
    if (EPI == 2) invs  += (size_t)i1 * sI1 + (size_t)i2 * sI2;

    __shared__ unsigned short S[(DB ? 2 : 1) * TILE];

    const int t    = threadIdx.x;
    const int lane = t & 63;
    const int w    = t >> 6;
    const int wm   = w & 1;
    const int wn   = w >> 1;
    const int m0   = blockIdx.x * TMv;
    const int n0   = blockIdx.y * TNv;

    // staging: 32 rows per pass, 8 threads/row, 16B each; global chunk XOR-swizzled by row
    const int rA = t >> 3;
    const int ch = ((t & 7) ^ (rA & 7)) * 8;
    const unsigned short* gA = A  + (size_t)(m0 + rA) * lda + ch;
    const unsigned short* gB = Bm + (size_t)(n0 + rA) * ldb + ch;

    const int fr = lane & 15;
    const int q  = lane >> 4;

    f32x4 acc[IT][JT];
#pragma unroll
    for (int i = 0; i < IT; ++i)
#pragma unroll
        for (int j = 0; j < JT; ++j) acc[i][j] = (f32x4){0.f, 0.f, 0.f, 0.f};

    auto stage = [&](unsigned short* Sb, int k0) {
#pragma unroll
        for (int p = 0; p < NPASS; ++p) {
            const unsigned short* src = (p < APASS)
                ? (gA + (size_t)p * 32 * lda + k0)
                : (gB + (size_t)(p - APASS) * 32 * ldb + k0);
            __builtin_amdgcn_global_load_lds(GBL(src), LDS(Sb + p * 2048 + t * 8), 16, 0, 0);
        }
    };
    auto kstep = [&](const unsigned short* As) {
        const unsigned short* Bs = As + TMv * 64;
#pragma unroll
        for (int ks = 0; ks < 2; ++ks) {
            const int slot = ((ks * 4 + q) ^ (fr & 7)) * 8;  // de-swizzle
            bf16x8 a[IT], b[JT];
#pragma unroll
            for (int i = 0; i < IT; ++i)
                a[i] = *(const bf16x8*)(As + (wm * WMv + i * 16 + fr) * 64 + slot);
#pragma unroll
            for (int j = 0; j < JT; ++j)
                b[j] = *(const bf16x8*)(Bs + (wn * WNv + j * 16 + fr) * 64 + slot);
#pragma unroll
            for (int i = 0; i < IT; ++i)
#pragma unroll
                for (int j = 0; j < JT; ++j)
                    acc[i][j] = __builtin_amdgcn_mfma_f32_16x16x32_bf16(a[i], b[j], acc[i][j], 0, 0, 0);
        }
    };

    if constexpr (DB) {
        const int nk = K >> 6;
        stage(S, 0);
        __syncthreads();
        int cur = 0;
        for (int kt = 0; kt < nk; ++kt) {
            // prefetch next k-tile into the other buffer; its readers were fenced
            // by the __syncthreads at the end of the previous iteration.
            if (kt + 1 < nk) stage(S + (cur ^ 1) * TILE, (kt + 1) << 6);
            kstep(S + cur * TILE);
            __syncthreads();   // implicit vmcnt(0): drains the prefetch issued a whole compute-phase ago
            cur ^= 1;
        }
    } else {
        for (int k0 = 0; k0 < K; k0 += 64) {
            stage(S, k0);
            __syncthreads();
            kstep(S);
            __syncthreads();
        }
    }

    // epilogue: C/D layout col = lane&15, row = (lane>>4)*4 + reg
#pragma unroll
    for (int i = 0; i < IT; ++i) {
#pragma unroll
        for (int r = 0; r < 4; ++r) {
            const int row = m0 + wm * WMv + i * 16 + q * 4 + r;
#pragma unroll
            for (int j = 0; j < JT; ++j) {
                const int col = n0 + wn * WNv + j * 16 + fr;
                float vv = acc[i][j][r] * alpha;
                if (EPI == 0) {
                    if constexpr (sizeof(OutT) == 4)
                        C[(size_t)row * ldc + col] = (OutT)vv;
                    else
                        ((unsigned short*)C)[(size_t)row * ldc + col] = f2bf(vv);
                } else if (EPI == 1) {
                    const float m = bf2f(maskb[(size_t)row * Lsz + col]);
                    vv = fminf(fmaxf(vv, -15.f), 15.f) * m;
                    vv = __expf(vv) * m;
                    ((unsigned short*)C)[(size_t)row * ldc + col] = f2bf(vv);
                } else {
                    vv *= invs[row];
                    ((unsigned short*)C)[(size_t)row * ldc + col] = f2bf(vv);
                }
            }
        }
    }
}

// ---- fp32->bf16 cast of all GEMM inputs + int32 mask -> bf16 {0,1} ----
__global__ __launch_bounds__(256) void cast_all(
    const float* __restrict__ q, const float* __restrict__ k, const float* __restrict__ v,
    const float* __restrict__ wq, const float* __restrict__ wk, const float* __restrict__ wv,
    const float* __restrict__ fw, const int* __restrict__ mask,
    unsigned short* __restrict__ qb, unsigned short* __restrict__ kb, unsigned short* __restrict__ vb,
    unsigned short* __restrict__ wqb, unsigned short* __restrict__ wkb, unsigned short* __restrict__ wvb,
    unsigned short* __restrict__ fwb, unsigned short* __restrict__ mb)
{
    const int gid = blockIdx.x * 256 + threadIdx.x;
    const int NQ = 262144;   // 1048576/4
    const int NW = 131072;   // 524288/4
    const int NF = 3 * NQ + 4 * NW;   // 1310720 float4 groups; wg 5120 is the clean split
    if (gid >= NF) {
        const int off = gid - NF;     // < 1048576 int4 groups of mask
        const int4 mi = ((const int4*)mask)[off];
        ushort4 o;
        o.x = mi.x ? 0x3F80 : 0;      // bf16(1.0f) / bf16(0.0f)
        o.y = mi.y ? 0x3F80 : 0;
        o.z = mi.z ? 0x3F80 : 0;
        o.w = mi.w ? 0x3F80 : 0;
        ((ushort4*)mb)[off] = o;
        return;
    }
    const float* src; unsigned short* dst; int off;
    if      (gid < NQ)            { src = q;  dst = qb;  off = gid; }
    else if (gid < 2 * NQ)        { src = k;  dst = kb;  off = gid - NQ; }
    else if (gid < 3 * NQ)        { src = v;  dst = vb;  off = gid - 2 * NQ; }
    else if (gid < 3 * NQ + NW)   { src = wq; dst = wqb; off = gid - 3 * NQ; }
    else if (gid < 3 * NQ + 2*NW) { src = wk; dst = wkb; off = gid - 3 * NQ - NW; }
    else if (gid < 3 * NQ + 3*NW) { src = wv; dst = wvb; off = gid - 3 * NQ - 2 * NW; }
    else                          { src = fw; dst = fwb; off = gid - 3 * NQ - 3 * NW; }
    float4 f = ((const float4*)src)[off];
    ushort4 o;
    o.x = f2bf(f.x); o.y = f2bf(f.y); o.z = f2bf(f.z); o.w = f2bf(f.w);
    ((ushort4*)dst)[off] = o;
}

// ---- normalize: wave per row, no barriers. read e bf16, write fp32 attn + invsum ----
__global__ __launch_bounds__(256) void norm_kernel(const unsigned short* __restrict__ e,
                                                   float* __restrict__ attn,
                                                   float* __restrict__ invsum)
{
    const int r    = blockIdx.x * 4 + (threadIdx.x >> 6);
    const int lane = threadIdx.x & 63;
    const unsigned short* rowp = e + (size_t)r * Lsz + lane * 16;

    union { uint4 v[2]; unsigned short u[16]; } buf;
    buf.v[0] = *(const uint4*)rowp;
    buf.v[1] = *(const uint4*)(rowp + 8);

    float f[16];
    float s = 0.f;
#pragma unroll
    for (int i = 0; i < 16; ++i) { f[i] = bf2f(buf.u[i]); s += f[i]; }
#pragma unroll
    for (int o = 1; o <= 32; o <<= 1) s += __shfl_xor(s, o, 64);
    const float inv = 1.0f / (s + 1e-6f);

    float* op = attn + (size_t)r * Lsz + lane * 16;
#pragma unroll
    for (int c = 0; c < 4; ++c) {
        float4 o4;
        o4.x = f[c * 4 + 0] * inv; o4.y = f[c * 4 + 1] * inv;
        o4.z = f[c * 4 + 2] * inv; o4.w = f[c * 4 + 3] * inv;
        *(float4*)(op + c * 4) = o4;
    }
    if (lane == 0) invsum[r] = inv;
}

// ---- sum 4 fc split-K partials + fc_b + residual -> LayerNorm -> out ----
__global__ __launch_bounds__(256) void ln_kernel(const float* __restrict__ gout,
                                                 const float* __restrict__ qin,
                                                 const float* __restrict__ fc_b,
                                                 const float* __restrict__ ln_g,
                                                 const float* __restrict__ ln_b,
                                                 float* __restrict__ out)
{
    const int row = blockIdx.x;
    const int t = threadIdx.x;
    const size_t idx = (size_t)row * Dsz + t;
    const size_t P = (size_t)NROWS * Dsz;
    const float val = gout[idx] + gout[idx + P] + gout[idx + 2 * P] + gout[idx + 3 * P]
                    + fc_b[t] + qin[idx];

    __shared__ float red[4];
    float s = val;
#pragma unroll
    for (int o = 32; o > 0; o >>= 1) s += __shfl_down(s, o, 64);
    const int lane = t & 63, w = t >> 6;
    if (lane == 0) red[w] = s;
    __syncthreads();
    const float mu = (red[0] + red[1] + red[2] + red[3]) * (1.0f / Dsz);
    __syncthreads();

    float d = val - mu;
    float s2 = d * d;
#pragma unroll
    for (int o = 32; o > 0; o >>= 1) s2 += __shfl_down(s2, o, 64);
    if (lane == 0) red[w] = s2;
    __syncthreads();
    const float var = (red[0] + red[1] + red[2] + red[3]) * (1.0f / Dsz);

    out[idx] = d * rsqrtf(var + 1e-5f) * ln_g[t] + ln_b[t];
}

extern "C" void kernel_launch(void* const* d_in, const int* in_sizes, int n_in,
                              void* d_out, int out_size, void* d_ws, size_t ws_size,
                              hipStream_t stream)
{
    const float* q    = (const float*)d_in[0];
    const int*   mask = (const int*)d_in[1];
    const float* k    = (const float*)d_in[2];
    const float* v    = (const float*)d_in[3];
    const float* w_qs = (const float*)d_in[4];
    const float* w_ks = (const float*)d_in[5];
    const float* w_vs = (const float*)d_in[6];
    const float* fc_w = (const float*)d_in[7];
    const float* fc_b = (const float*)d_in[8];
    const float* ln_g = (const float*)d_in[9];
    const float* ln_b = (const float*)d_in[10];

    float* out  = (float*)d_out;                       // [B,L,D]
    float* attn = (float*)d_out + (size_t)NROWS * Dsz; // [H*B,L,L] fp32 normalized

    // Workspace layout (ushort units)
    unsigned short* wsu = (unsigned short*)d_ws;
    unsigned short* qh     = wsu;                                  // [4096,2048]
    unsigned short* kh     = qh + (size_t)NROWS * HD;              // [4096,2048]
    unsigned short* q_bf   = kh + (size_t)NROWS * HD;              // [4096,256] x3 (contiguous: z-indexed)
    unsigned short* k_bf   = q_bf + (size_t)NROWS * Dsz;
    unsigned short* v_bf   = k_bf + (size_t)NROWS * Dsz;
    unsigned short* wq_bf  = v_bf + (size_t)NROWS * Dsz;           // [2048,256] x3 (contiguous)
    unsigned short* wk_bf  = wq_bf + (size_t)HD * Dsz;
    unsigned short* wv_bf  = wk_bf + (size_t)HD * Dsz;
    unsigned short* vt     = wv_bf + (size_t)HD * Dsz;             // [B,2048,1024]
    unsigned short* attn_e = vt + (size_t)Bsz * HD * Lsz;          // [32,1024,1024] unnormalized e
    unsigned short* attnv  = attn_e + (size_t)32 * Lsz * Lsz;      // [4096,2048]
    unsigned short* fcw_bf = attnv + (size_t)NROWS * HD;           // [256,2048]
    float*          invsum = (float*)(fcw_bf + (size_t)Dsz * HD);  // [32768]
    float*          fcout  = invsum + 32768;                       // [4,4096,256] split-K partials
    unsigned short* maskb  = (unsigned short*)(fcout + (size_t)4 * NROWS * Dsz); // [B,L,L] bf16 {0,1}

    dim3 blk(256);

    // 0) cast everything to bf16 (incl. mask -> bf16 multiplicand)
    cast_all<<<dim3(9216), blk, 0, stream>>>(q, k, v, w_qs, w_ks, w_vs, fc_w, mask,
                                             q_bf, k_bf, v_bf, wq_bf, wk_bf, wv_bf, fcw_bf, maskb);

    // 1) q/k projections, one dispatch: z=0 -> qh, z=1 -> kh. 128x128 tile (m97-best), 3 wg/CU, grid 32x16x2.
    {
        dim3 grid(NROWS / 128, HD / 128, 2);
        gemm_bt<128, 128, unsigned short, 0, 3, 0><<<grid, blk, 0, stream>>>(q_bf, wq_bf, qh,
            Dsz, Dsz, Dsz, HD, 2,
            0, (long long)NROWS * Dsz, 0, (long long)HD * Dsz, 0, (long long)NROWS * HD,
            1.0f, nullptr, 0, nullptr, 0, 0);
    }

    // 2) vt[b] = w_vs @ v_b^T : [2048,1024] per b. 128x128 dbuf (grid-limited 2 wg/CU), grid 16x8x4 = 512.
    {
        dim3 grid(HD / 128, Lsz / 128, Bsz);
        gemm_bt<128, 128, unsigned short, 0, 2, 1><<<grid, blk, 0, stream>>>(wv_bf, v_bf, vt,
            Dsz, Dsz, Dsz, Lsz, 1,
            0, 0, (long long)Lsz * Dsz, 0, (long long)HD * Lsz, 0,
            1.0f, nullptr, 0, nullptr, 0, 0);
    }

    // 3) scores + clamp/mask/exp: attn_e[z] = exp(clamp(qh kh^T /16)*m)*m (bf16). 128x128, 3 wg/CU, grid 8x8x32.
    {
        dim3 grid(Lsz / 128, Lsz / 128, Hsz * Bsz);
        gemm_bt<128, 128, unsigned short, 1, 3, 0><<<grid, blk, 0, stream>>>(qh, kh, attn_e,
            Dsz, HD, HD, Lsz, Bsz,
            Dsz, (long long)Lsz * HD, Dsz, (long long)Lsz * HD,
            (long long)Bsz * Lsz * Lsz, (long long)Lsz * Lsz,
            INV_TEMP, maskb, (long long)Lsz * Lsz, nullptr, 0, 0);
    }

    // 4) normalize: fp32 attn output + per-row 1/(sum+eps). Wave per row.
    norm_kernel<<<dim3(32 * Lsz / 4), blk, 0, stream>>>(attn_e, attn, invsum);

    // 5) pv: attnv = (e @ vt^T) * inv[row]. 128x128 dbuf (grid-limited 2 wg/CU), K=1024 deep, grid 8x2x32 = 512.
    {
        dim3 grid(Lsz / 128, Dsz / 128, Hsz * Bsz);
        gemm_bt<128, 128, unsigned short, 2, 2, 1><<<grid, blk, 0, stream>>>(attn_e, vt, attnv,
            Lsz, Lsz, Lsz, HD, Bsz,
            (long long)Bsz * Lsz * Lsz, (long long)Lsz * Lsz,
            (long long)Dsz * Lsz, (long long)HD * Lsz,
            Dsz, (long long)Lsz * HD,
            1.0f, nullptr, 0, invsum, (long long)Bsz * Lsz, (long long)Lsz);
    }

    // 6) fc split-K x4: fcout[p] = attnv[:, p*512:+512] @ fc_w[:, p*512:+512]^T.
    //    64x128 dbuf, grid 64x2x4 = 512 (was 256 = 1 wg/CU starved).
    {
        dim3 grid(NROWS / 64, Dsz / 128, 4);
        gemm_bt<64, 128, float, 0, 3, 1><<<grid, blk, 0, stream>>>(attnv, fcw_bf, fcout,
            512, HD, HD, Dsz, 4,
            0, 512, 0, 512, 0, (long long)NROWS * Dsz,
            1.0f, nullptr, 0, nullptr, 0, 0);
    }

    // 7) sum partials + bias + residual + LayerNorm
    ln_kernel<<<dim3(NROWS), blk, 0, stream>>>(fcout, q, fc_b, ln_g, ln_b, out);
}